// Round 10
// baseline (112.567 us; speedup 1.0000x reference)
//
#include <hip/hip_runtime.h>
#include <hip/hip_bf16.h>

#define B_ 4
#define N_ 1024
#define M_ 32
#define C_ 128
#define D_ 64
#define BM_ (B_*M_)   // 128 independent attention problems

typedef float f32x4 __attribute__((ext_vector_type(4)));
typedef float f32x16 __attribute__((ext_vector_type(16)));
typedef short short8 __attribute__((ext_vector_type(8)));
typedef short short4v __attribute__((ext_vector_type(4)));

#define EXP2(x) __builtin_amdgcn_exp2f(x)

static __device__ __forceinline__ int cvtpk_bf16(float lo, float hi) {
  int r;
  asm volatile("v_cvt_pk_bf16_f32 %0, %1, %2" : "=v"(r) : "v"(lo), "v"(hi));
  return r;
}
static __device__ __forceinline__ void plswap(int& a, int& b) {
  asm volatile("v_permlane32_swap_b32 %0, %1" : "+v"(a), "+v"(b));
}

// ---------------------------------------------------------------------------
// Kernel 0: transpose weights to bf16, concatenated [256 cols][128 k].
// cols 0-63 = w_q scaled by (1/sqrt(64))*log2(e), 64-127 = w_k, 128-255 = w_v.
// ---------------------------------------------------------------------------
__global__ __launch_bounds__(256) void prep_weights(
    const float* __restrict__ wq, const float* __restrict__ wk,
    const float* __restrict__ wv, __hip_bfloat16* __restrict__ wt) {
  int idx = blockIdx.x * 256 + threadIdx.x;   // 0 .. 32767
  int col = idx >> 7;      // 0..255
  int kk  = idx & 127;     // 0..127
  float v;
  if (col < 64)        v = wq[kk * 64 + col] * (0.125f * 1.44269504088896f);
  else if (col < 128)  v = wk[kk * 64 + (col - 64)];
  else                 v = wv[kk * 128 + (col - 128)];
  wt[col * 128 + kk] = __float2bfloat16(v);
}

// ---------------------------------------------------------------------------
// Kernel 1: LayerNorm (register-based) + Q/K/V projections via MFMA.
// Grid: 128 (b,m) * 8 row-tiles of 128. Block: 512 threads (8 waves).
// ---------------------------------------------------------------------------
__global__ __launch_bounds__(512, 6) void ln_qkv(
    const float* __restrict__ x, const float* __restrict__ gamma,
    const float* __restrict__ beta, const __hip_bfloat16* __restrict__ wt,
    __hip_bfloat16* __restrict__ q, __hip_bfloat16* __restrict__ k,
    __hip_bfloat16* __restrict__ vt) {
  __shared__ alignas(16) __hip_bfloat16 xn[128][136];  // 34.8 KB

  int bid = blockIdx.x;
  int bm  = bid >> 3;
  int n0  = (bid & 7) * 128;
  int b   = bm >> 5, m = bm & 31;
  int tid = threadIdx.x;

  const float* xbase = x + ((((size_t)b * N_ + n0) * M_ + m) * C_);
  int c4 = tid & 31;
  float4 vch[8];
  #pragma unroll
  for (int it = 0; it < 8; ++it) {
    int r = (it * 512 + tid) >> 5;
    vch[it] = *reinterpret_cast<const float4*>(xbase + (size_t)r * (M_ * C_) + c4 * 4);
  }
  float4 g4 = *reinterpret_cast<const float4*>(gamma + c4 * 4);
  float4 b4 = *reinterpret_cast<const float4*>(beta + c4 * 4);

  #pragma unroll
  for (int it = 0; it < 8; ++it) {
    int r = (it * 512 + tid) >> 5;
    float4 v = vch[it];
    float s  = (v.x + v.y) + (v.z + v.w);
    float sq = (v.x * v.x + v.y * v.y) + (v.z * v.z + v.w * v.w);
    s  += __shfl_xor(s, 1);  sq += __shfl_xor(sq, 1);
    s  += __shfl_xor(s, 2);  sq += __shfl_xor(sq, 2);
    s  += __shfl_xor(s, 4);  sq += __shfl_xor(sq, 4);
    s  += __shfl_xor(s, 8);  sq += __shfl_xor(sq, 8);
    s  += __shfl_xor(s, 16); sq += __shfl_xor(sq, 16);
    float mean = s * (1.f / 128.f);
    float var  = sq * (1.f / 128.f) - mean * mean;
    float rstd = rsqrtf(var + 1e-3f);
    alignas(8) __hip_bfloat16 tmp[4];
    tmp[0] = __float2bfloat16((v.x - mean) * rstd * g4.x + b4.x);
    tmp[1] = __float2bfloat16((v.y - mean) * rstd * g4.y + b4.y);
    tmp[2] = __float2bfloat16((v.z - mean) * rstd * g4.z + b4.z);
    tmp[3] = __float2bfloat16((v.w - mean) * rstd * g4.w + b4.w);
    *reinterpret_cast<short4v*>(&xn[r][c4 * 4]) =
        *reinterpret_cast<const short4v*>(tmp);
  }
  __syncthreads();

  int w = tid >> 6, l = tid & 63, lr = l & 15, lh = l >> 4;
  int ct0 = w, ct1 = w + 8;

  short8 wf0[4], wf1[4];
  #pragma unroll
  for (int h = 0; h < 4; ++h) {
    wf0[h] = *reinterpret_cast<const short8*>(
        &wt[(ct0 * 16 + lr) * 128 + h * 32 + lh * 8]);
    wf1[h] = *reinterpret_cast<const short8*>(
        &wt[(ct1 * 16 + lr) * 128 + h * 32 + lh * 8]);
  }

  const f32x4 fzero = {0.f, 0.f, 0.f, 0.f};
  int col0 = ct0 * 16 + lr;
  int cV   = w * 16 + lr;
  #pragma unroll
  for (int rt = 0; rt < 8; ++rt) {
    short8 a[4];
    #pragma unroll
    for (int h = 0; h < 4; ++h)
      a[h] = *reinterpret_cast<const short8*>(&xn[rt * 16 + lr][h * 32 + lh * 8]);
    f32x4 acc0 = fzero, acc1 = fzero;
    #pragma unroll
    for (int h = 0; h < 4; ++h) {
      acc0 = __builtin_amdgcn_mfma_f32_16x16x32_bf16(a[h], wf0[h], acc0, 0, 0, 0);
      acc1 = __builtin_amdgcn_mfma_f32_16x16x32_bf16(a[h], wf1[h], acc1, 0, 0, 0);
    }
    int nb = n0 + rt * 16 + lh * 4;
    if (ct0 < 4) {
      #pragma unroll
      for (int r = 0; r < 4; ++r)
        q[((size_t)bm * N_ + nb + r) * D_ + col0] = __float2bfloat16(acc0[r]);
    } else {
      #pragma unroll
      for (int r = 0; r < 4; ++r)
        k[((size_t)bm * N_ + nb + r) * D_ + (col0 - 64)] = __float2bfloat16(acc0[r]);
    }
    alignas(8) __hip_bfloat16 tmp[4];
    #pragma unroll
    for (int r = 0; r < 4; ++r) tmp[r] = __float2bfloat16(acc1[r]);
    *reinterpret_cast<short4v*>(&vt[((size_t)bm * C_ + cV) * N_ + nb]) =
        *reinterpret_cast<const short4v*>(tmp);
  }
}

// ---------------------------------------------------------------------------
// Kernel 2: flash attention per (b,m), swapped-QK^T, in-register P.
// Softmax is SPECULATIVE: p = exp2(s - m_run_old) issues immediately (TRANS
// pipe, shift-invariant); the max tree + defer-gate resolve concurrently on
// the VALU; rare trigger corrects p/acc/l by fac. m_run init 0 (no peel).
// K double-buffered LDS, V single-buffered (two barriers bracket PV).
// LDS 36864 B. Grid 1024, XCD-swizzled. Block 256 = 4 waves x 32 q-rows.
// ---------------------------------------------------------------------------
__global__ __launch_bounds__(256, 2) void attn_kernel(
    const float* __restrict__ x, const float* __restrict__ lam,
    const __hip_bfloat16* __restrict__ q, const __hip_bfloat16* __restrict__ k,
    const __hip_bfloat16* __restrict__ vt, float* __restrict__ out) {
  __shared__ alignas(16) __hip_bfloat16 kbuf[2][64 * 72];   // 9216 B each
  __shared__ alignas(16) __hip_bfloat16 vbuf[128 * 72];     // 18432 B single

  int h   = blockIdx.x;
  int s_  = h >> 3;
  int bm  = (s_ >> 3) * 8 + (h & 7);
  int n0  = (s_ & 7) * 128;
  int b   = bm >> 5, m = bm & 31;
  int tid = threadIdx.x;
  int w = tid >> 6, l = tid & 63;
  int lq = l & 31, hi = l >> 5;

  const __hip_bfloat16* kbase = k + (size_t)bm * N_ * D_;
  const __hip_bfloat16* vbase = vt + (size_t)bm * C_ * N_;

  // staging chunk coords (16B chunks)
  int kr0 = tid >> 3,          kc = tid & 7;          // K rows 0..31 / 32..63
  int kr1 = (tid + 256) >> 3;
  int vr[4], vc = tid & 7;
  #pragma unroll
  for (int i = 0; i < 4; ++i) vr[i] = (tid + i * 256) >> 3;

  // Q fragments (B operand of S^T): lane = col q, k = d = 16*s + 8*hi + i
  short8 qf[4];
  {
    int n = n0 + w * 32 + lq;
    const __hip_bfloat16* qp = q + ((size_t)bm * N_ + n) * D_;
    #pragma unroll
    for (int s = 0; s < 4; ++s)
      qf[s] = *reinterpret_cast<const short8*>(qp + s * 16 + hi * 8);
  }

  f32x16 acc[4];
  const f32x16 z16 = {0.f,0.f,0.f,0.f,0.f,0.f,0.f,0.f,
                      0.f,0.f,0.f,0.f,0.f,0.f,0.f,0.f};
  #pragma unroll
  for (int ct = 0; ct < 4; ++ct) acc[ct] = z16;
  float m_run = 0.f, l_run = 0.f;   // m_run=0: softmax is shift-invariant;
                                    // gate corrects if scores exceed +8

  short8 kreg[2], vreg[4];
  // ---- prologue: stage tile 0 (K -> kbuf[0], V -> vbuf) ----
  kreg[0] = *reinterpret_cast<const short8*>(&kbase[(size_t)kr0 * D_ + kc * 8]);
  kreg[1] = *reinterpret_cast<const short8*>(&kbase[(size_t)kr1 * D_ + kc * 8]);
  #pragma unroll
  for (int i = 0; i < 4; ++i)
    vreg[i] = *reinterpret_cast<const short8*>(&vbase[(size_t)vr[i] * N_ + vc * 8]);
  *reinterpret_cast<short8*>(&kbuf[0][kr0 * 72 + kc * 8]) = kreg[0];
  *reinterpret_cast<short8*>(&kbuf[0][kr1 * 72 + kc * 8]) = kreg[1];
  #pragma unroll
  for (int i = 0; i < 4; ++i)
    *reinterpret_cast<short8*>(&vbuf[vr[i] * 72 + vc * 8]) = vreg[i];
  __syncthreads();

  for (int t = 0; t < 16; ++t) {
    int cur = t & 1, nxt = cur ^ 1;
    // ---- issue next tile's global loads (latency hides under compute) ----
    if (t < 15) {
      int j0n = (t + 1) * 64;
      kreg[0] = *reinterpret_cast<const short8*>(&kbase[(size_t)(j0n + kr0) * D_ + kc * 8]);
      kreg[1] = *reinterpret_cast<const short8*>(&kbase[(size_t)(j0n + kr1) * D_ + kc * 8]);
      #pragma unroll
      for (int i = 0; i < 4; ++i)
        vreg[i] = *reinterpret_cast<const short8*>(&vbase[(size_t)vr[i] * N_ + j0n + vc * 8]);
    }

    const __hip_bfloat16* kt = kbuf[cur];

    // ---- S^T = K * Q^T : st[t32] holds kj rows (reg-local), q cols (lane)
    f32x16 st[2];
    st[0] = z16; st[1] = z16;
    #pragma unroll
    for (int s = 0; s < 4; ++s) {
      short8 kf0 = *reinterpret_cast<const short8*>(&kt[lq * 72 + s * 16 + hi * 8]);
      st[0] = __builtin_amdgcn_mfma_f32_32x32x16_bf16(kf0, qf[s], st[0], 0, 0, 0);
      short8 kf1 = *reinterpret_cast<const short8*>(&kt[(32 + lq) * 72 + s * 16 + hi * 8]);
      st[1] = __builtin_amdgcn_mfma_f32_32x32x16_bf16(kf1, qf[s], st[1], 0, 0, 0);
    }

    // ---- max tree (VALU) — runs CONCURRENT with the exps below ----
    float mx;
    {
      float t8[8];
      #pragma unroll
      for (int i = 0; i < 8; ++i)
        t8[i] = fmaxf(fmaxf(st[0][i], st[0][i + 8]), fmaxf(st[1][i], st[1][i + 8]));
      float a0 = fmaxf(fmaxf(t8[0], t8[1]), fmaxf(t8[2], t8[3]));
      float a1 = fmaxf(fmaxf(t8[4], t8[5]), fmaxf(t8[6], t8[7]));
      mx = fmaxf(a0, a1);
      mx = fmaxf(mx, __shfl_xor(mx, 32));
    }

    // ---- speculative exp with OLD m_run (TRANS pipe; shift-invariant) ----
    #pragma unroll
    for (int i = 0; i < 16; ++i) {
      st[0][i] = EXP2(st[0][i] - m_run);
      st[1][i] = EXP2(st[1][i] - m_run);
    }

    // ---- rare correction: max grew past THR=8 ----
    if (__any(mx > m_run + 8.0f)) {
      float mnew = fmaxf(m_run, mx);
      float fac = EXP2(m_run - mnew);
      m_run = mnew;
      l_run *= fac;
      #pragma unroll
      for (int i = 0; i < 16; ++i) { st[0][i] *= fac; st[1][i] *= fac; }
      #pragma unroll
      for (int reg = 0; reg < 16; ++reg) {
        int qi = (reg & 3) + 8 * (reg >> 2) + 4 * hi;
        float f = __shfl(fac, qi);
        #pragma unroll
        for (int ct = 0; ct < 4; ++ct) acc[ct][reg] *= f;
      }
    }

    // ---- build PV A-fragments fully in-register (cvt_pk + permlane) ----
    union W4 { int w[4]; short8 s8; } pf[4];
    #pragma unroll
    for (int t32 = 0; t32 < 2; ++t32) {
      int A = cvtpk_bf16(st[t32][0], st[t32][1]);
      int Bw = cvtpk_bf16(st[t32][2], st[t32][3]);
      int Cw = cvtpk_bf16(st[t32][4], st[t32][5]);
      int Dw = cvtpk_bf16(st[t32][6], st[t32][7]);
      plswap(A, Cw);
      plswap(Bw, Dw);
      pf[t32 * 2].w[0] = A;  pf[t32 * 2].w[1] = Bw;
      pf[t32 * 2].w[2] = Cw; pf[t32 * 2].w[3] = Dw;
      int E = cvtpk_bf16(st[t32][8], st[t32][9]);
      int F = cvtpk_bf16(st[t32][10], st[t32][11]);
      int G = cvtpk_bf16(st[t32][12], st[t32][13]);
      int H = cvtpk_bf16(st[t32][14], st[t32][15]);
      plswap(E, G);
      plswap(F, H);
      pf[t32 * 2 + 1].w[0] = E; pf[t32 * 2 + 1].w[1] = F;
      pf[t32 * 2 + 1].w[2] = G; pf[t32 * 2 + 1].w[3] = H;
    }

    // ---- stage next K into the other kbuf (double-buffered, no hazard) ----
    if (t < 15) {
      *reinterpret_cast<short8*>(&kbuf[nxt][kr0 * 72 + kc * 8]) = kreg[0];
      *reinterpret_cast<short8*>(&kbuf[nxt][kr1 * 72 + kc * 8]) = kreg[1];
    }

    __syncthreads();   // pre-PV: V(t) writes (from t-1) visible to all waves

    // ---- O += P @ V ----
    #pragma unroll
    for (int kb = 0; kb < 4; ++kb) {
      #pragma unroll
      for (int ct = 0; ct < 4; ++ct) {
        short8 vf = *reinterpret_cast<const short8*>(
            &vbuf[(ct * 32 + lq) * 72 + kb * 16 + hi * 8]);
        acc[ct] = __builtin_amdgcn_mfma_f32_32x32x16_bf16(pf[kb].s8, vf, acc[ct], 0, 0, 0);
      }
    }

    // ---- l sum tree (only needed at epilogue; overlaps PV tail) ----
    {
      float s8[8];
      #pragma unroll
      for (int i = 0; i < 8; ++i)
        s8[i] = (st[0][i] + st[0][i + 8]) + (st[1][i] + st[1][i + 8]);
      float rs = ((s8[0] + s8[1]) + (s8[2] + s8[3])) +
                 ((s8[4] + s8[5]) + (s8[6] + s8[7]));
      rs += __shfl_xor(rs, 32);
      l_run += rs;
    }

    // ---- post-PV barrier, then overwrite vbuf with V(t+1) ----
    if (t < 15) {
      __syncthreads();
      #pragma unroll
      for (int i = 0; i < 4; ++i)
        *reinterpret_cast<short8*>(&vbuf[vr[i] * 72 + vc * 8]) = vreg[i];
    }
  }

  // ---- epilogue: out = x + (O / l) * lam ----
  float inv = 1.0f / l_run;
  float rlv[16];
  #pragma unroll
  for (int reg = 0; reg < 16; ++reg) {
    int qi = (reg & 3) + 8 * (reg >> 2) + 4 * hi;
    rlv[reg] = __shfl(inv, qi);
  }
  #pragma unroll
  for (int ct = 0; ct < 4; ++ct) {
    int c = ct * 32 + lq;
    float lamc = lam[c];
    #pragma unroll
    for (int reg = 0; reg < 16; ++reg) {
      int qi = (reg & 3) + 8 * (reg >> 2) + 4 * hi;
      int n = n0 + w * 32 + qi;
      size_t idx = ((((size_t)b * N_ + n) * M_ + m) * C_) + c;
      out[idx] = x[idx] + acc[ct][reg] * rlv[reg] * lamc;
    }
  }
}

// ---------------------------------------------------------------------------
extern "C" void kernel_launch(void* const* d_in, const int* in_sizes, int n_in,
                              void* d_out, int out_size, void* d_ws, size_t ws_size,
                              hipStream_t stream) {
  const float* x     = (const float*)d_in[0];
  const float* gamma = (const float*)d_in[1];
  const float* beta  = (const float*)d_in[2];
  const float* wq    = (const float*)d_in[3];
  const float* wk    = (const float*)d_in[4];
  const float* wv    = (const float*)d_in[5];
  const float* lam   = (const float*)d_in[6];
  float* out = (float*)d_out;

  __hip_bfloat16* ws = (__hip_bfloat16*)d_ws;
  __hip_bfloat16* wt = ws;                        // 256*128
  __hip_bfloat16* q  = wt + 256 * 128;            // 128*1024*64
  __hip_bfloat16* k  = q + (size_t)BM_ * N_ * D_; // 128*1024*64
  __hip_bfloat16* vt = k + (size_t)BM_ * N_ * D_; // 128*128*1024 (transposed)

  prep_weights<<<128, 256, 0, stream>>>(wq, wk, wv, wt);
  ln_qkv<<<BM_ * (N_ / 128), 512, 0, stream>>>(x, gamma, beta, wt, q, k, vt);
  attn_kernel<<<BM_ * (N_ / 128), 256, 0, stream>>>(x, lam, q, k, vt, out);
}

// Round 11
// 112.139 us; speedup vs baseline: 1.0038x; 1.0038x over previous
//
#include <hip/hip_runtime.h>
#include <hip/hip_bf16.h>

#define B_ 4
#define N_ 1024
#define M_ 32
#define C_ 128
#define D_ 64
#define BM_ (B_*M_)   // 128 independent attention problems

typedef float f32x4 __attribute__((ext_vector_type(4)));
typedef float f32x16 __attribute__((ext_vector_type(16)));
typedef short short8 __attribute__((ext_vector_type(8)));
typedef short short4v __attribute__((ext_vector_type(4)));

#define EXP2(x) __builtin_amdgcn_exp2f(x)

static __device__ __forceinline__ int cvtpk_bf16(float lo, float hi) {
  int r;
  asm volatile("v_cvt_pk_bf16_f32 %0, %1, %2" : "=v"(r) : "v"(lo), "v"(hi));
  return r;
}
static __device__ __forceinline__ void plswap(int& a, int& b) {
  asm volatile("v_permlane32_swap_b32 %0, %1" : "+v"(a), "+v"(b));
}

// ---------------------------------------------------------------------------
// Kernel 0: transpose weights to bf16, concatenated [256 cols][128 k].
// cols 0-63 = w_q scaled by (1/sqrt(64))*log2(e), 64-127 = w_k, 128-255 = w_v.
// ---------------------------------------------------------------------------
__global__ __launch_bounds__(256) void prep_weights(
    const float* __restrict__ wq, const float* __restrict__ wk,
    const float* __restrict__ wv, __hip_bfloat16* __restrict__ wt) {
  int idx = blockIdx.x * 256 + threadIdx.x;   // 0 .. 32767
  int col = idx >> 7;      // 0..255
  int kk  = idx & 127;     // 0..127
  float v;
  if (col < 64)        v = wq[kk * 64 + col] * (0.125f * 1.44269504088896f);
  else if (col < 128)  v = wk[kk * 64 + (col - 64)];
  else                 v = wv[kk * 128 + (col - 128)];
  wt[col * 128 + kk] = __float2bfloat16(v);
}

// ---------------------------------------------------------------------------
// Kernel 1: LayerNorm (register-based) + Q/K/V projections via MFMA.
// Grid: 128 (b,m) * 8 row-tiles of 128. Block: 512 threads (8 waves).
// ---------------------------------------------------------------------------
__global__ __launch_bounds__(512, 6) void ln_qkv(
    const float* __restrict__ x, const float* __restrict__ gamma,
    const float* __restrict__ beta, const __hip_bfloat16* __restrict__ wt,
    __hip_bfloat16* __restrict__ q, __hip_bfloat16* __restrict__ k,
    __hip_bfloat16* __restrict__ vt) {
  __shared__ alignas(16) __hip_bfloat16 xn[128][136];  // 34.8 KB

  int bid = blockIdx.x;
  int bm  = bid >> 3;
  int n0  = (bid & 7) * 128;
  int b   = bm >> 5, m = bm & 31;
  int tid = threadIdx.x;

  const float* xbase = x + ((((size_t)b * N_ + n0) * M_ + m) * C_);
  int c4 = tid & 31;
  float4 vch[8];
  #pragma unroll
  for (int it = 0; it < 8; ++it) {
    int r = (it * 512 + tid) >> 5;
    vch[it] = *reinterpret_cast<const float4*>(xbase + (size_t)r * (M_ * C_) + c4 * 4);
  }
  float4 g4 = *reinterpret_cast<const float4*>(gamma + c4 * 4);
  float4 b4 = *reinterpret_cast<const float4*>(beta + c4 * 4);

  #pragma unroll
  for (int it = 0; it < 8; ++it) {
    int r = (it * 512 + tid) >> 5;
    float4 v = vch[it];
    float s  = (v.x + v.y) + (v.z + v.w);
    float sq = (v.x * v.x + v.y * v.y) + (v.z * v.z + v.w * v.w);
    s  += __shfl_xor(s, 1);  sq += __shfl_xor(sq, 1);
    s  += __shfl_xor(s, 2);  sq += __shfl_xor(sq, 2);
    s  += __shfl_xor(s, 4);  sq += __shfl_xor(sq, 4);
    s  += __shfl_xor(s, 8);  sq += __shfl_xor(sq, 8);
    s  += __shfl_xor(s, 16); sq += __shfl_xor(sq, 16);
    float mean = s * (1.f / 128.f);
    float var  = sq * (1.f / 128.f) - mean * mean;
    float rstd = rsqrtf(var + 1e-3f);
    alignas(8) __hip_bfloat16 tmp[4];
    tmp[0] = __float2bfloat16((v.x - mean) * rstd * g4.x + b4.x);
    tmp[1] = __float2bfloat16((v.y - mean) * rstd * g4.y + b4.y);
    tmp[2] = __float2bfloat16((v.z - mean) * rstd * g4.z + b4.z);
    tmp[3] = __float2bfloat16((v.w - mean) * rstd * g4.w + b4.w);
    *reinterpret_cast<short4v*>(&xn[r][c4 * 4]) =
        *reinterpret_cast<const short4v*>(tmp);
  }
  __syncthreads();

  int w = tid >> 6, l = tid & 63, lr = l & 15, lh = l >> 4;
  int ct0 = w, ct1 = w + 8;

  short8 wf0[4], wf1[4];
  #pragma unroll
  for (int h = 0; h < 4; ++h) {
    wf0[h] = *reinterpret_cast<const short8*>(
        &wt[(ct0 * 16 + lr) * 128 + h * 32 + lh * 8]);
    wf1[h] = *reinterpret_cast<const short8*>(
        &wt[(ct1 * 16 + lr) * 128 + h * 32 + lh * 8]);
  }

  const f32x4 fzero = {0.f, 0.f, 0.f, 0.f};
  int col0 = ct0 * 16 + lr;
  int cV   = w * 16 + lr;
  #pragma unroll
  for (int rt = 0; rt < 8; ++rt) {
    short8 a[4];
    #pragma unroll
    for (int h = 0; h < 4; ++h)
      a[h] = *reinterpret_cast<const short8*>(&xn[rt * 16 + lr][h * 32 + lh * 8]);
    f32x4 acc0 = fzero, acc1 = fzero;
    #pragma unroll
    for (int h = 0; h < 4; ++h) {
      acc0 = __builtin_amdgcn_mfma_f32_16x16x32_bf16(a[h], wf0[h], acc0, 0, 0, 0);
      acc1 = __builtin_amdgcn_mfma_f32_16x16x32_bf16(a[h], wf1[h], acc1, 0, 0, 0);
    }
    int nb = n0 + rt * 16 + lh * 4;
    if (ct0 < 4) {
      #pragma unroll
      for (int r = 0; r < 4; ++r)
        q[((size_t)bm * N_ + nb + r) * D_ + col0] = __float2bfloat16(acc0[r]);
    } else {
      #pragma unroll
      for (int r = 0; r < 4; ++r)
        k[((size_t)bm * N_ + nb + r) * D_ + (col0 - 64)] = __float2bfloat16(acc0[r]);
    }
    alignas(8) __hip_bfloat16 tmp[4];
    #pragma unroll
    for (int r = 0; r < 4; ++r) tmp[r] = __float2bfloat16(acc1[r]);
    *reinterpret_cast<short4v*>(&vt[((size_t)bm * C_ + cV) * N_ + nb]) =
        *reinterpret_cast<const short4v*>(tmp);
  }
}

// ---------------------------------------------------------------------------
// Kernel 2: flash attention, delayed-PV software pipeline (T15):
// per tile t issue QK^T(t) then immediately PV(t-1) (independent MFMA
// streams fill the matrix pipe); softmax(t)/pf-build run on VALU while the
// PV MFMAs execute. V is TRIPLE-buffered (slot j%3: write (t+1)%3, read
// (t+2)%3 -- distinct, and each write->read pair crosses >=1 barrier).
// K double-buffered. Speculative softmax (exp with old m_run, rare gate
// correction; acc rescale has a reg dependency on PV(t-1), ordering safe).
// One barrier per tile. LDS 73728 B -> 2 blocks/CU. Grid 1024, XCD-swizzled.
// ---------------------------------------------------------------------------
__global__ __launch_bounds__(256, 2) void attn_kernel(
    const float* __restrict__ x, const float* __restrict__ lam,
    const __hip_bfloat16* __restrict__ q, const __hip_bfloat16* __restrict__ k,
    const __hip_bfloat16* __restrict__ vt, float* __restrict__ out) {
  __shared__ alignas(16) __hip_bfloat16 kbuf[2][64 * 72];   // 9216 B each
  __shared__ alignas(16) __hip_bfloat16 vbuf[3][128 * 72];  // 18432 B each

  int h   = blockIdx.x;
  int s_  = h >> 3;
  int bm  = (s_ >> 3) * 8 + (h & 7);
  int n0  = (s_ & 7) * 128;
  int b   = bm >> 5, m = bm & 31;
  int tid = threadIdx.x;
  int w = tid >> 6, l = tid & 63;
  int lq = l & 31, hi = l >> 5;

  const __hip_bfloat16* kbase = k + (size_t)bm * N_ * D_;
  const __hip_bfloat16* vbase = vt + (size_t)bm * C_ * N_;

  // staging chunk coords (16B chunks)
  int kr0 = tid >> 3,          kc = tid & 7;          // K rows 0..31 / 32..63
  int kr1 = (tid + 256) >> 3;
  int vr[4], vc = tid & 7;
  #pragma unroll
  for (int i = 0; i < 4; ++i) vr[i] = (tid + i * 256) >> 3;

  // Q fragments (B operand of S^T): lane = col q, k = d = 16*s + 8*hi + i
  short8 qf[4];
  {
    int n = n0 + w * 32 + lq;
    const __hip_bfloat16* qp = q + ((size_t)bm * N_ + n) * D_;
    #pragma unroll
    for (int s = 0; s < 4; ++s)
      qf[s] = *reinterpret_cast<const short8*>(qp + s * 16 + hi * 8);
  }

  f32x16 acc[4];
  const f32x16 z16 = {0.f,0.f,0.f,0.f,0.f,0.f,0.f,0.f,
                      0.f,0.f,0.f,0.f,0.f,0.f,0.f,0.f};
  #pragma unroll
  for (int ct = 0; ct < 4; ++ct) acc[ct] = z16;
  float m_run = 0.f, l_run = 0.f;   // spec-softmax: shift-invariant, gate at +8

  union W4 { int w[4]; short8 s8; } pf[4];   // P fragments, live across iters
  short8 kreg[2], vreg[4];

  // ---- prologue: stage tile 0 (K -> kbuf[0], V -> vbuf[0]) ----
  kreg[0] = *reinterpret_cast<const short8*>(&kbase[(size_t)kr0 * D_ + kc * 8]);
  kreg[1] = *reinterpret_cast<const short8*>(&kbase[(size_t)kr1 * D_ + kc * 8]);
  #pragma unroll
  for (int i = 0; i < 4; ++i)
    vreg[i] = *reinterpret_cast<const short8*>(&vbase[(size_t)vr[i] * N_ + vc * 8]);
  *reinterpret_cast<short8*>(&kbuf[0][kr0 * 72 + kc * 8]) = kreg[0];
  *reinterpret_cast<short8*>(&kbuf[0][kr1 * 72 + kc * 8]) = kreg[1];
  #pragma unroll
  for (int i = 0; i < 4; ++i)
    *reinterpret_cast<short8*>(&vbuf[0][vr[i] * 72 + vc * 8]) = vreg[i];
  __syncthreads();

  #pragma unroll
  for (int t = 0; t < 16; ++t) {
    int kcur = t & 1, knxt = kcur ^ 1;
    int vw = (t + 1) % 3;          // V slot being written (tile t+1)
    int vrd = (t + 2) % 3;         // V slot of tile t-1 (== (t-1)%3)

    // ---- issue next tile's global loads ----
    if (t < 15) {
      int j0n = (t + 1) * 64;
      kreg[0] = *reinterpret_cast<const short8*>(&kbase[(size_t)(j0n + kr0) * D_ + kc * 8]);
      kreg[1] = *reinterpret_cast<const short8*>(&kbase[(size_t)(j0n + kr1) * D_ + kc * 8]);
      #pragma unroll
      for (int i = 0; i < 4; ++i)
        vreg[i] = *reinterpret_cast<const short8*>(&vbase[(size_t)vr[i] * N_ + j0n + vc * 8]);
    }

    const __hip_bfloat16* kt = kbuf[kcur];

    // ---- QK^T(t): S^T = K * Q^T ----
    f32x16 st[2];
    st[0] = z16; st[1] = z16;
    #pragma unroll
    for (int s = 0; s < 4; ++s) {
      short8 kf0 = *reinterpret_cast<const short8*>(&kt[lq * 72 + s * 16 + hi * 8]);
      st[0] = __builtin_amdgcn_mfma_f32_32x32x16_bf16(kf0, qf[s], st[0], 0, 0, 0);
      short8 kf1 = *reinterpret_cast<const short8*>(&kt[(32 + lq) * 72 + s * 16 + hi * 8]);
      st[1] = __builtin_amdgcn_mfma_f32_32x32x16_bf16(kf1, qf[s], st[1], 0, 0, 0);
    }

    // ---- PV(t-1): independent of softmax(t); executes under the VALU work
    if (t > 0) {
      const __hip_bfloat16* vtt = vbuf[vrd];
      #pragma unroll
      for (int kb = 0; kb < 4; ++kb) {
        #pragma unroll
        for (int ct = 0; ct < 4; ++ct) {
          short8 vf = *reinterpret_cast<const short8*>(
              &vtt[(ct * 32 + lq) * 72 + kb * 16 + hi * 8]);
          acc[ct] = __builtin_amdgcn_mfma_f32_32x32x16_bf16(pf[kb].s8, vf, acc[ct], 0, 0, 0);
        }
      }
    }

    // ---- max tree (VALU, overlaps PV execution) ----
    float mx;
    {
      float t8[8];
      #pragma unroll
      for (int i = 0; i < 8; ++i)
        t8[i] = fmaxf(fmaxf(st[0][i], st[0][i + 8]), fmaxf(st[1][i], st[1][i + 8]));
      float a0 = fmaxf(fmaxf(t8[0], t8[1]), fmaxf(t8[2], t8[3]));
      float a1 = fmaxf(fmaxf(t8[4], t8[5]), fmaxf(t8[6], t8[7]));
      mx = fmaxf(a0, a1);
      mx = fmaxf(mx, __shfl_xor(mx, 32));
    }

    // ---- speculative exp with OLD m_run (TRANS pipe; shift-invariant) ----
    #pragma unroll
    for (int i = 0; i < 16; ++i) {
      st[0][i] = EXP2(st[0][i] - m_run);
      st[1][i] = EXP2(st[1][i] - m_run);
    }

    // ---- rare correction: max grew past THR=8 (acc dep orders after PV) ----
    if (__any(mx > m_run + 8.0f)) {
      float mnew = fmaxf(m_run, mx);
      float fac = EXP2(m_run - mnew);
      m_run = mnew;
      l_run *= fac;
      #pragma unroll
      for (int i = 0; i < 16; ++i) { st[0][i] *= fac; st[1][i] *= fac; }
      #pragma unroll
      for (int reg = 0; reg < 16; ++reg) {
        int qi = (reg & 3) + 8 * (reg >> 2) + 4 * hi;
        float f = __shfl(fac, qi);
        #pragma unroll
        for (int ct = 0; ct < 4; ++ct) acc[ct][reg] *= f;
      }
    }

    // ---- build PV A-fragments for tile t (consumed next iteration) ----
    #pragma unroll
    for (int t32 = 0; t32 < 2; ++t32) {
      int A = cvtpk_bf16(st[t32][0], st[t32][1]);
      int Bw = cvtpk_bf16(st[t32][2], st[t32][3]);
      int Cw = cvtpk_bf16(st[t32][4], st[t32][5]);
      int Dw = cvtpk_bf16(st[t32][6], st[t32][7]);
      plswap(A, Cw);
      plswap(Bw, Dw);
      pf[t32 * 2].w[0] = A;  pf[t32 * 2].w[1] = Bw;
      pf[t32 * 2].w[2] = Cw; pf[t32 * 2].w[3] = Dw;
      int E = cvtpk_bf16(st[t32][8], st[t32][9]);
      int F = cvtpk_bf16(st[t32][10], st[t32][11]);
      int G = cvtpk_bf16(st[t32][12], st[t32][13]);
      int H = cvtpk_bf16(st[t32][14], st[t32][15]);
      plswap(E, G);
      plswap(F, H);
      pf[t32 * 2 + 1].w[0] = E; pf[t32 * 2 + 1].w[1] = F;
      pf[t32 * 2 + 1].w[2] = G; pf[t32 * 2 + 1].w[3] = H;
    }

    // ---- l sum tree (VALU; also overlaps PV execution) ----
    {
      float s8[8];
      #pragma unroll
      for (int i = 0; i < 8; ++i)
        s8[i] = (st[0][i] + st[0][i + 8]) + (st[1][i] + st[1][i + 8]);
      float rs = ((s8[0] + s8[1]) + (s8[2] + s8[3])) +
                 ((s8[4] + s8[5]) + (s8[6] + s8[7]));
      rs += __shfl_xor(rs, 32);
      l_run += rs;
    }

    // ---- stage tile t+1 into kbuf[knxt], vbuf[vw]; one barrier per tile ----
    if (t < 15) {
      *reinterpret_cast<short8*>(&kbuf[knxt][kr0 * 72 + kc * 8]) = kreg[0];
      *reinterpret_cast<short8*>(&kbuf[knxt][kr1 * 72 + kc * 8]) = kreg[1];
      #pragma unroll
      for (int i = 0; i < 4; ++i)
        *reinterpret_cast<short8*>(&vbuf[vw][vr[i] * 72 + vc * 8]) = vreg[i];
      __syncthreads();
    }
  }

  // ---- final PV(15): V(15) lives in slot 15%3 = 0; no writes since t=14 ----
  {
    const __hip_bfloat16* vtt = vbuf[0];
    #pragma unroll
    for (int kb = 0; kb < 4; ++kb) {
      #pragma unroll
      for (int ct = 0; ct < 4; ++ct) {
        short8 vf = *reinterpret_cast<const short8*>(
            &vtt[(ct * 32 + lq) * 72 + kb * 16 + hi * 8]);
        acc[ct] = __builtin_amdgcn_mfma_f32_32x32x16_bf16(pf[kb].s8, vf, acc[ct], 0, 0, 0);
      }
    }
  }

  // ---- epilogue: out = x + (O / l) * lam ----
  float inv = 1.0f / l_run;
  float rlv[16];
  #pragma unroll
  for (int reg = 0; reg < 16; ++reg) {
    int qi = (reg & 3) + 8 * (reg >> 2) + 4 * hi;
    rlv[reg] = __shfl(inv, qi);
  }
  #pragma unroll
  for (int ct = 0; ct < 4; ++ct) {
    int c = ct * 32 + lq;
    float lamc = lam[c];
    #pragma unroll
    for (int reg = 0; reg < 16; ++reg) {
      int qi = (reg & 3) + 8 * (reg >> 2) + 4 * hi;
      int n = n0 + w * 32 + qi;
      size_t idx = ((((size_t)b * N_ + n) * M_ + m) * C_) + c;
      out[idx] = x[idx] + acc[ct][reg] * rlv[reg] * lamc;
    }
  }
}

// ---------------------------------------------------------------------------
extern "C" void kernel_launch(void* const* d_in, const int* in_sizes, int n_in,
                              void* d_out, int out_size, void* d_ws, size_t ws_size,
                              hipStream_t stream) {
  const float* x     = (const float*)d_in[0];
  const float* gamma = (const float*)d_in[1];
  const float* beta  = (const float*)d_in[2];
  const float* wq    = (const float*)d_in[3];
  const float* wk    = (const float*)d_in[4];
  const float* wv    = (const float*)d_in[5];
  const float* lam   = (const float*)d_in[6];
  float* out = (float*)d_out;

  __hip_bfloat16* ws = (__hip_bfloat16*)d_ws;
  __hip_bfloat16* wt = ws;                        // 256*128
  __hip_bfloat16* q  = wt + 256 * 128;            // 128*1024*64
  __hip_bfloat16* k  = q + (size_t)BM_ * N_ * D_; // 128*1024*64
  __hip_bfloat16* vt = k + (size_t)BM_ * N_ * D_; // 128*128*1024 (transposed)

  prep_weights<<<128, 256, 0, stream>>>(wq, wk, wv, wt);
  ln_qkv<<<BM_ * (N_ / 128), 512, 0, stream>>>(x, gamma, beta, wt, q, k, vt);
  attn_kernel<<<BM_ * (N_ / 128), 256, 0, stream>>>(x, lam, q, k, vt, out);
}